// Round 10
// baseline (218.021 us; speedup 1.0000x reference)
//
#include <hip/hip_runtime.h>
#include <cstdint>

typedef unsigned long long u64;
typedef unsigned int u32;
typedef unsigned short u16;

typedef __attribute__((ext_vector_type(8))) short short8;
typedef __attribute__((ext_vector_type(4))) float f32x4;
typedef _Float16 half8 __attribute__((ext_vector_type(8)));

#define EPSF 1e-3f
#define CAP1 780000u
#define CAP2 780000u

__device__ __forceinline__ int pidx(int br, int t, int b, int n, int h) {
    return (((br * 4 + t) * 8 + b) * 512 + n) * 8 + h;
}

// truncation split: x = hi + lo + eps, |eps| <= |x|*2^-16
__device__ __forceinline__ void split1(float f, short& h, short& l) {
    u32 u = __float_as_uint(f);
    u32 hb = u & 0xFFFF0000u;
    float r = f - __uint_as_float(hb);
    h = (short)(hb >> 16);
    l = (short)(__float_as_uint(r) >> 16);
}

// async global->LDS, 16B per lane; dest = wave-uniform base + lane*16
__device__ __forceinline__ void gload_lds16(const void* g, void* lds_base, int lane) {
#if __has_builtin(__builtin_amdgcn_global_load_lds)
    __builtin_amdgcn_global_load_lds(
        (const __attribute__((address_space(1))) unsigned int*)g,
        (__attribute__((address_space(3))) unsigned int*)lds_base, 16, 0, 0);
#else
    ((short8*)lds_base)[lane] = *(const short8*)g;
#endif
}

__global__ void k_zero(u32* p) {
    if (threadIdx.x == 0 && blockIdx.x == 0) *p = 0;
}

// ---------------- merged pre-split: W (blocks 0..511) + x (blocks 512..4607) ----------------
__global__ __launch_bounds__(256) void k_split_xw(
    const float* __restrict__ x,
    const float* __restrict__ qw, const float* __restrict__ kw,
    const float* __restrict__ vw, const float* __restrict__ pw,
    short* __restrict__ wfh, short* __restrict__ wfl,
    short* __restrict__ xfh, short* __restrict__ xfl, u32* __restrict__ flags1)
{
    const int bid = blockIdx.x;
    const int tid = threadIdx.x;
    if (bid < 512) {
        int idx = bid * 256 + tid;                // [0, 131072)
        if (idx == 0) flags1[0] = 0;
        int lane = idx & 63;
        int kb = (idx >> 6) & 15;
        int dt = (idx >> 10) & 31;
        int mat = idx >> 15;
        const float* W = mat == 0 ? qw : (mat == 1 ? kw : (mat == 2 ? vw : pw));
        int d = dt * 16 + (lane & 15);
        int k = kb * 32 + ((lane >> 4) & 3) * 8;
        const float* p = W + (size_t)d * 512 + k;
        float4 a = *(const float4*)p, b = *(const float4*)(p + 4);
        float fv[8] = {a.x, a.y, a.z, a.w, b.x, b.y, b.z, b.w};
        short8 vh, vl;
        #pragma unroll
        for (int j = 0; j < 8; ++j) { short hh, ll; split1(fv[j], hh, ll); vh[j] = hh; vl[j] = ll; }
        *(short8*)&wfh[(size_t)idx * 8] = vh;
        *(short8*)&wfl[(size_t)idx * 8] = vl;
    } else {
        int idx = (bid - 512) * 256 + tid;        // [0, 1048576)
        int lane = idx & 63;
        int msub = (idx >> 6) & 3;
        int kb = (idx >> 8) & 15;
        int t = (idx >> 12) & 3;
        int mt = idx >> 14;                       // [0, 64)
        int l15 = lane & 15, g = lane >> 4;
        int row = mt * 64 + msub * 16 + l15;
        int col = kb * 32 + g * 8;
        const float* p = &x[((size_t)(t * 4096 + row)) * 512 + col];
        float4 a = *(const float4*)p, b = *(const float4*)(p + 4);
        float fv[8] = {a.x, a.y, a.z, a.w, b.x, b.y, b.z, b.w};
        short8 vh, vl;
        #pragma unroll
        for (int j = 0; j < 8; ++j) { short hh, ll; split1(fv[j], hh, ll); vh[j] = hh; vl[j] = ll; }
        *(short8*)&xfh[(size_t)idx * 8] = vh;
        *(short8*)&xfl[(size_t)idx * 8] = vl;
    }
}

// ---------------- K1 p2: depth-2 counted-vmcnt pipelined 3-branch bf16x3 MFMA GEMM + T5 --------
// grid (64, 12), 512 threads (8 waves, 32m x 32d each); A dbuf LDS 64KB, B ping-pong regs
__global__ __launch_bounds__(512, 2) void k_branch_p2(
    const short* __restrict__ xfh, const short* __restrict__ xfl,
    const short* __restrict__ wfh, const short* __restrict__ wfl,
    const float* __restrict__ bi0, const float* __restrict__ ga0,
    const float* __restrict__ be0, const float* __restrict__ mu0, const float* __restrict__ va0,
    const float* __restrict__ bi1, const float* __restrict__ ga1,
    const float* __restrict__ be1, const float* __restrict__ mu1, const float* __restrict__ va1,
    const float* __restrict__ bi2, const float* __restrict__ ga2,
    const float* __restrict__ be2, const float* __restrict__ mu2, const float* __restrict__ va2,
    u64* __restrict__ packed, u32* __restrict__ flags)
{
    __shared__ __align__(16) short Ah[2][8192];   // 2 x 16KB
    __shared__ __align__(16) short Al[2][8192];   // 2 x 16KB

    const int tid = threadIdx.x;
    const int wave = tid >> 6, lane = tid & 63;
    const int l15 = lane & 15, g = lane >> 4;
    const int mhalf = wave & 1, dquad = wave >> 1;
    const int ta = wave >> 1, pr = wave & 1;      // A-staging role
    const int mt = blockIdx.x;
    const int m0 = mt * 64;
    const int gy = blockIdx.y;
    const int branch = gy >> 2;
    const int hp = gy & 3;
    const int d0 = hp * 128;

    const float *bp = bi0, *gp = ga0, *bep = be0, *mup = mu0, *vap = va0;
    if (branch == 1) { bp = bi1; gp = ga1; bep = be1; mup = mu1; vap = va1; }
    if (branch == 2) { bp = bi2; gp = ga2; bep = be2; mup = mu2; vap = va2; }

    f32x4 acc[4][2][2];
    #pragma unroll
    for (int t = 0; t < 4; ++t)
        #pragma unroll
        for (int ms = 0; ms < 2; ++ms)
            #pragma unroll
            for (int ds = 0; ds < 2; ++ds) acc[t][ms][ds] = (f32x4)0.0f;

    auto stageA = [&](int kb, short* AhB, short* AlB) {
        const size_t abase = ((size_t)((mt * 4 + ta) * 16 + kb) * 4) * 512;
        #pragma unroll
        for (int s = 0; s < 2; ++s) {
            int msub = pr * 2 + s;
            gload_lds16(&xfh[abase + (size_t)msub * 512 + lane * 8], &AhB[(ta * 4 + msub) * 512], lane);
            gload_lds16(&xfl[abase + (size_t)msub * 512 + lane * 8], &AlB[(ta * 4 + msub) * 512], lane);
        }
    };
    auto loadB = [&](int kb, short8* b) {
        #pragma unroll
        for (int ds = 0; ds < 2; ++ds) {
            const size_t src = ((size_t)((branch * 32 + hp * 8 + dquad * 2 + ds) * 16 + kb) * 64 + lane) * 8;
            b[ds * 2 + 0] = *(const short8*)&wfh[src];
            b[ds * 2 + 1] = *(const short8*)&wfl[src];
        }
    };
    auto compute = [&](const short* AhB, const short* AlB, const short8* b) {
        __builtin_amdgcn_s_setprio(1);
        #pragma unroll
        for (int t = 0; t < 4; ++t)
            #pragma unroll
            for (int ms = 0; ms < 2; ++ms) {
                int ch = ((t * 4 + mhalf * 2 + ms) * 64 + lane) * 8;
                short8 ah = *(const short8*)&AhB[ch];
                short8 al = *(const short8*)&AlB[ch];
                #pragma unroll
                for (int ds = 0; ds < 2; ++ds) {
                    f32x4 c = acc[t][ms][ds];
                    c = __builtin_amdgcn_mfma_f32_16x16x32_bf16(ah, b[ds * 2 + 0], c, 0, 0, 0);
                    c = __builtin_amdgcn_mfma_f32_16x16x32_bf16(ah, b[ds * 2 + 1], c, 0, 0, 0);
                    c = __builtin_amdgcn_mfma_f32_16x16x32_bf16(al, b[ds * 2 + 0], c, 0, 0, 0);
                    acc[t][ms][ds] = c;
                }
            }
        __builtin_amdgcn_s_setprio(0);
    };

    short8 bA[4], bB[4];
    // prologue: queue = [s0(4)] [b0(4)] [s1(4)] -> vmcnt(8) completes s0 only
    stageA(0, Ah[0], Al[0]);
    loadB(0, bA);
    stageA(1, Ah[1], Al[1]);
    asm volatile("s_waitcnt vmcnt(8)" ::: "memory");
    __builtin_amdgcn_s_barrier();

    for (int kb = 0; kb < 14; kb += 2) {
        // even: compute kb from buf0/bA; stage kb+2 -> buf0
        loadB(kb + 1, bB);
        compute(Ah[0], Al[0], bA);                 // bA regs auto-waited (oldest)
        asm volatile("s_waitcnt lgkmcnt(0)" ::: "memory");
        __builtin_amdgcn_s_barrier();              // all waves done reading buf0
        stageA(kb + 2, Ah[0], Al[0]);
        asm volatile("s_waitcnt vmcnt(8)" ::: "memory");   // completes stage(kb+1)
        __builtin_amdgcn_s_barrier();              // buf1 (kb+1) now valid for all
        // odd: compute kb+1 from buf1/bB; stage kb+3 -> buf1
        loadB(kb + 2, bA);
        compute(Ah[1], Al[1], bB);
        asm volatile("s_waitcnt lgkmcnt(0)" ::: "memory");
        __builtin_amdgcn_s_barrier();
        stageA(kb + 3, Ah[1], Al[1]);
        asm volatile("s_waitcnt vmcnt(8)" ::: "memory");   // completes stage(kb+2)
        __builtin_amdgcn_s_barrier();
    }
    // kb = 14
    loadB(15, bB);
    compute(Ah[0], Al[0], bA);
    asm volatile("s_waitcnt lgkmcnt(0)" ::: "memory");
    __builtin_amdgcn_s_barrier();
    asm volatile("s_waitcnt vmcnt(4)" ::: "memory");       // completes stage(15)
    __builtin_amdgcn_s_barrier();
    // kb = 15
    compute(Ah[1], Al[1], bB);

    float scv[2], muv[2], bev[2], biv[2];
    #pragma unroll
    for (int ds = 0; ds < 2; ++ds) {
        int d = d0 + dquad * 32 + ds * 16 + l15;
        scv[ds] = gp[d] / sqrtf(vap[d] + 1e-5f);
        muv[ds] = mup[d]; bev[ds] = bep[d]; biv[ds] = bp[d];
    }

    __syncthreads();
    u64* Pk = (u64*)Ah;                           // 4KB alias (Ah dead now)
    Pk[tid] = 0ull;
    __syncthreads();

    const int word = dquad >> 1;
    const int shbase = (dquad & 1) * 32;
    #pragma unroll
    for (int ms = 0; ms < 2; ++ms)
        #pragma unroll
        for (int ds = 0; ds < 2; ++ds)
            #pragma unroll
            for (int r = 0; r < 4; ++r) {
                int rowl = mhalf * 32 + ms * 16 + g * 4 + r;
                float v = 0.f, mm = 1e9f;
                #pragma unroll
                for (int t = 0; t < 4; ++t) {
                    float yb = (acc[t][ms][ds][r] + biv[ds] - muv[ds]) * scv[ds] + bev[ds];
                    v = v + (yb - v) * 0.5f;
                    mm = fminf(mm, fabsf(v - 1.0f));
                    bool s = v >= 1.0f;
                    u64 bal = __ballot(s);
                    if (s) v = 0.f;
                    if (l15 == 0) {
                        u64 b16 = (bal >> (g * 16)) & 0xFFFFull;
                        if (b16) atomicOr(&Pk[(t * 64 + rowl) * 2 + word], b16 << (shbase + ds * 16));
                    }
                }
                if (mm < EPSF) {
                    u32 ix = atomicAdd(flags, 1u);
                    if (ix < CAP1)
                        flags[4 + ix] = ((u32)branch << 21) | ((u32)(m0 + rowl) << 9)
                                      | (u32)(d0 + dquad * 32 + ds * 16 + l15);
                }
            }
    __syncthreads();
    {
        int t = tid >> 7, rem = tid & 127, row = rem >> 1, w = rem & 1;
        int m = m0 + row;
        packed[pidx(branch, t, m >> 9, m & 511, hp * 2 + w)] = Pk[(t * 64 + row) * 2 + w];
    }
}

// ---------------- K3 f2: p-branch MFMA with in-kernel s2 expand, 1 barrier/K-step + T5 ---------
// grid (64, 8), 512 threads (8 waves, 32m x 16d each); A dbuf 32KB (spikes exact, no lo)
__global__ __launch_bounds__(512, 2) void k_pbranch_f2(
    const u16* __restrict__ s2,
    const short* __restrict__ wfh, const short* __restrict__ wfl,
    const float* __restrict__ pbi, const float* __restrict__ pga,
    const float* __restrict__ pbe, const float* __restrict__ pmu, const float* __restrict__ pva,
    float* __restrict__ out, u32* __restrict__ flags)
{
    __shared__ __align__(16) short Ab[2][8192];   // 2 x 16KB

    const int tid = threadIdx.x;
    const int wave = tid >> 6, lane = tid & 63;
    const int l15 = lane & 15, g = lane >> 4;
    const int mhalf = wave & 1, dq = wave >> 1;
    const int m0 = blockIdx.x * 64;
    const int d0 = blockIdx.y * 64;

    // expand role
    const int et = tid >> 7, em = (tid >> 1) & 63, echh = tid & 1;
    const u32* s2row = (const u32*)&s2[((size_t)(et * 4096 + m0 + em)) * 32];

    f32x4 acc[4][2];
    #pragma unroll
    for (int t = 0; t < 4; ++t)
        #pragma unroll
        for (int ms = 0; ms < 2; ++ms) acc[t][ms] = (f32x4)0.0f;

    auto loadB = [&](int kb, short8* b) {
        const size_t src = ((size_t)((96 + (d0 >> 4) + dq) * 16 + kb) * 64 + lane) * 8;
        b[0] = *(const short8*)&wfh[src];
        b[1] = *(const short8*)&wfl[src];
    };
    auto expand = [&](u32 bits, short* buf) {
        #pragma unroll
        for (int cc = 0; cc < 2; ++cc) {
            int c = echh * 2 + cc;
            short8 vv;
            #pragma unroll
            for (int j = 0; j < 8; ++j)
                vv[j] = ((bits >> (c * 8 + j)) & 1u) ? (short)0x3F80 : (short)0;
            int ch = (et * 4 + (em >> 4)) * 64 + (((em & 15) ^ (c << 2)) + c * 16);
            *(short8*)&buf[ch * 8] = vv;
        }
    };
    const int chp = ((l15 ^ (g << 2)) + g * 16);
    auto compute = [&](const short* buf, const short8* b) {
        __builtin_amdgcn_s_setprio(1);
        #pragma unroll
        for (int t = 0; t < 4; ++t)
            #pragma unroll
            for (int ms = 0; ms < 2; ++ms) {
                short8 ah = *(const short8*)&buf[((t * 4 + mhalf * 2 + ms) * 64 + chp) * 8];
                f32x4 c = acc[t][ms];
                c = __builtin_amdgcn_mfma_f32_16x16x32_bf16(ah, b[0], c, 0, 0, 0);
                c = __builtin_amdgcn_mfma_f32_16x16x32_bf16(ah, b[1], c, 0, 0, 0);
                acc[t][ms] = c;
            }
        __builtin_amdgcn_s_setprio(0);
    };

    short8 bA[2], bB[2];
    u32 sA = s2row[0];                            // bits for kb=0
    u32 sB = s2row[1];                            // bits for kb=1
    loadB(0, bA);
    loadB(1, bB);
    expand(sA, Ab[0]);
    __syncthreads();

    for (int kb = 0; kb < 16; kb += 2) {
        // even: compute(kb) on Ab[0]/bA; expand(kb+1) -> Ab[1]
        if (kb < 14) sA = s2row[kb + 2];
        expand(sB, Ab[1]);
        compute(Ab[0], bA);
        if (kb < 14) loadB(kb + 2, bA);
        __syncthreads();
        // odd: compute(kb+1) on Ab[1]/bB; expand(kb+2) -> Ab[0]
        if (kb < 14) {
            sB = s2row[kb + 3];
            expand(sA, Ab[0]);
        }
        compute(Ab[1], bB);
        if (kb < 14) loadB(kb + 3, bB);
        __syncthreads();
    }

    const int d = d0 + dq * 16 + l15;
    const float scv = pga[d] / sqrtf(pva[d] + 1e-5f);
    const float muv = pmu[d], bev = pbe[d], biv = pbi[d];

    #pragma unroll
    for (int ms = 0; ms < 2; ++ms)
        #pragma unroll
        for (int r = 0; r < 4; ++r) {
            int row = m0 + mhalf * 32 + ms * 16 + g * 4 + r;
            float v = 0.f, mm = 1e9f;
            #pragma unroll
            for (int t = 0; t < 4; ++t) {
                float yb = (acc[t][ms][r] + biv - muv) * scv + bev;
                v = v + (yb - v) * 0.5f;
                mm = fminf(mm, fabsf(v - 1.0f));
                bool s = v >= 1.0f;
                out[((size_t)(t * 4096 + row)) * 512 + d] = s ? 1.0f : 0.0f;
                if (s) v = 0.f;
            }
            if (mm < EPSF) {
                u32 ix = atomicAdd(flags, 1u);
                if (ix < CAP2) flags[4 + ix] = ((u32)row << 9) | (u32)d;
            }
        }
}

// ---------------- V4 fallback kernels (in-kernel split), used when ws is small ----------------
__global__ __launch_bounds__(512, 2) void k_branch_v4(
    const float* __restrict__ x,
    const short* __restrict__ wfh, const short* __restrict__ wfl,
    const float* __restrict__ bi0, const float* __restrict__ ga0,
    const float* __restrict__ be0, const float* __restrict__ mu0, const float* __restrict__ va0,
    const float* __restrict__ bi1, const float* __restrict__ ga1,
    const float* __restrict__ be1, const float* __restrict__ mu1, const float* __restrict__ va1,
    const float* __restrict__ bi2, const float* __restrict__ ga2,
    const float* __restrict__ be2, const float* __restrict__ mu2, const float* __restrict__ va2,
    u64* __restrict__ packed, u32* __restrict__ flags)
{
    __shared__ __align__(16) short Ah[4 * 4 * 64 * 8];
    __shared__ __align__(16) short Al[4 * 4 * 64 * 8];
    __shared__ __align__(16) short Bh[8 * 64 * 8];
    __shared__ __align__(16) short Bl[8 * 64 * 8];

    const int tid = threadIdx.x;
    const int wave = tid >> 6, lane = tid & 63;
    const int l15 = lane & 15, g = lane >> 4;
    const int mhalf = wave & 1, dquad = wave >> 1;
    const int m0 = blockIdx.x * 64;
    const int gy = blockIdx.y;
    const int branch = gy >> 2;
    const int hp = gy & 3;
    const int d0 = hp * 128;

    const float *bp = bi0, *gp = ga0, *bep = be0, *mup = mu0, *vap = va0;
    if (branch == 1) { bp = bi1; gp = ga1; bep = be1; mup = mu1; vap = va1; }
    if (branch == 2) { bp = bi2; gp = ga2; bep = be2; mup = mu2; vap = va2; }

    f32x4 acc[4][2][2];
    #pragma unroll
    for (int t = 0; t < 4; ++t)
        #pragma unroll
        for (int ms = 0; ms < 2; ++ms)
            #pragma unroll
            for (int ds = 0; ds < 2; ++ds) acc[t][ms][ds] = (f32x4)0.0f;

    for (int k0 = 0; k0 < 512; k0 += 32) {
        const int kb = k0 >> 5;
        __syncthreads();
        {
            const size_t src = ((size_t)((branch * 32 + hp * 8 + wave) * 16 + kb) * 64 + lane) * 8;
            gload_lds16(&wfh[src], &Bh[wave * 512], lane);
            gload_lds16(&wfl[src], &Bl[wave * 512], lane);
        }
        #pragma unroll
        for (int i = 0; i < 2; ++i) {
            int f = tid + i * 512;
            int c = f & 3, m = (f >> 2) & 63, t = f >> 8;
            const float* xp = &x[(size_t)(t * 4096 + m0 + m) * 512 + k0 + c * 8];
            float4 a = *(const float4*)xp, b = *(const float4*)(xp + 4);
            float fv[8] = {a.x, a.y, a.z, a.w, b.x, b.y, b.z, b.w};
            short8 vh, vl;
            #pragma unroll
            for (int j = 0; j < 8; ++j) { short hh, ll; split1(fv[j], hh, ll); vh[j] = hh; vl[j] = ll; }
            int ch = (t * 4 + (m >> 4)) * 64 + (((m & 15) ^ (c << 2)) + c * 16);
            *(short8*)&Ah[ch * 8] = vh;
            *(short8*)&Al[ch * 8] = vl;
        }
        __syncthreads();

        short8 bh[2], bl[2];
        #pragma unroll
        for (int ds = 0; ds < 2; ++ds) {
            int chunk = (dquad * 2 + ds) * 64 + lane;
            bh[ds] = *(short8*)&Bh[chunk * 8];
            bl[ds] = *(short8*)&Bl[chunk * 8];
        }
        const int chp = ((l15 ^ (g << 2)) + g * 16);
        #pragma unroll
        for (int t = 0; t < 4; ++t)
            #pragma unroll
            for (int ms = 0; ms < 2; ++ms) {
                int ch = ((t * 4 + mhalf * 2 + ms) * 64 + chp) * 8;
                short8 ah = *(short8*)&Ah[ch];
                short8 al = *(short8*)&Al[ch];
                #pragma unroll
                for (int ds = 0; ds < 2; ++ds) {
                    f32x4 c = acc[t][ms][ds];
                    c = __builtin_amdgcn_mfma_f32_16x16x32_bf16(ah, bh[ds], c, 0, 0, 0);
                    c = __builtin_amdgcn_mfma_f32_16x16x32_bf16(ah, bl[ds], c, 0, 0, 0);
                    c = __builtin_amdgcn_mfma_f32_16x16x32_bf16(al, bh[ds], c, 0, 0, 0);
                    acc[t][ms][ds] = c;
                }
            }
    }

    float scv[2], muv[2], bev[2], biv[2];
    #pragma unroll
    for (int ds = 0; ds < 2; ++ds) {
        int d = d0 + dquad * 32 + ds * 16 + l15;
        scv[ds] = gp[d] / sqrtf(vap[d] + 1e-5f);
        muv[ds] = mup[d]; bev[ds] = bep[d]; biv[ds] = bp[d];
    }

    __syncthreads();
    u64* Pk = (u64*)Bh;
    Pk[tid] = 0ull;
    __syncthreads();

    const int word = dquad >> 1;
    const int shbase = (dquad & 1) * 32;
    #pragma unroll
    for (int ms = 0; ms < 2; ++ms)
        #pragma unroll
        for (int ds = 0; ds < 2; ++ds)
            #pragma unroll
            for (int r = 0; r < 4; ++r) {
                int rowl = mhalf * 32 + ms * 16 + g * 4 + r;
                float v = 0.f, mm = 1e9f;
                #pragma unroll
                for (int t = 0; t < 4; ++t) {
                    float yb = (acc[t][ms][ds][r] + biv[ds] - muv[ds]) * scv[ds] + bev[ds];
                    v = v + (yb - v) * 0.5f;
                    mm = fminf(mm, fabsf(v - 1.0f));
                    bool s = v >= 1.0f;
                    u64 bal = __ballot(s);
                    if (s) v = 0.f;
                    if (l15 == 0) {
                        u64 b16 = (bal >> (g * 16)) & 0xFFFFull;
                        if (b16) atomicOr(&Pk[(t * 64 + rowl) * 2 + word], b16 << (shbase + ds * 16));
                    }
                }
                if (mm < EPSF) {
                    u32 ix = atomicAdd(flags, 1u);
                    if (ix < CAP1)
                        flags[4 + ix] = ((u32)branch << 21) | ((u32)(m0 + rowl) << 9)
                                      | (u32)(d0 + dquad * 32 + ds * 16 + l15);
                }
            }
    __syncthreads();
    {
        int t = tid >> 7, rem = tid & 127, row = rem >> 1, w = rem & 1;
        int m = m0 + row;
        packed[pidx(branch, t, m >> 9, m & 511, hp * 2 + w)] = Pk[(t * 64 + row) * 2 + w];
    }
}

// ---------------- repair1: fp64 recompute of flagged (branch,m,d) chains ----------------
__global__ __launch_bounds__(256) void k_repair1(
    const float* __restrict__ x,
    const float* __restrict__ w0, const float* __restrict__ bi0,
    const float* __restrict__ ga0, const float* __restrict__ be0,
    const float* __restrict__ mu0, const float* __restrict__ va0,
    const float* __restrict__ w1, const float* __restrict__ bi1,
    const float* __restrict__ ga1, const float* __restrict__ be1,
    const float* __restrict__ mu1, const float* __restrict__ va1,
    const float* __restrict__ w2, const float* __restrict__ bi2,
    const float* __restrict__ ga2, const float* __restrict__ be2,
    const float* __restrict__ mu2, const float* __restrict__ va2,
    const u32* __restrict__ flags, u64* __restrict__ packed)
{
    u32 n = flags[0]; if (n > CAP1) n = CAP1;
    int gw = (blockIdx.x * 256 + threadIdx.x) >> 6;
    int lane = threadIdx.x & 63;
    int nw = gridDim.x * 4;
    for (u32 i = gw; i < n; i += nw) {
        u32 e = flags[4 + i];
        int branch = e >> 21, m = (e >> 9) & 4095, d = e & 511;
        const float* W  = branch == 0 ? w0  : (branch == 1 ? w1  : w2);
        const float* bi = branch == 0 ? bi0 : (branch == 1 ? bi1 : bi2);
        const float* ga = branch == 0 ? ga0 : (branch == 1 ? ga1 : ga2);
        const float* be = branch == 0 ? be0 : (branch == 1 ? be1 : be2);
        const float* mu = branch == 0 ? mu0 : (branch == 1 ? mu1 : mu2);
        const float* va = branch == 0 ? va0 : (branch == 1 ? va1 : va2);
        const float* wr = W + (size_t)d * 512 + lane * 8;
        float4 wa = *(const float4*)wr, wb = *(const float4*)(wr + 4);
        double dots[4];
        #pragma unroll
        for (int t = 0; t < 4; ++t) {
            const float* xr = x + ((size_t)(t * 4096 + m)) * 512 + lane * 8;
            float4 xa = *(const float4*)xr, xb = *(const float4*)(xr + 4);
            double s = (double)xa.x * wa.x + (double)xa.y * wa.y + (double)xa.z * wa.z + (double)xa.w * wa.w
                     + (double)xb.x * wb.x + (double)xb.y * wb.y + (double)xb.z * wb.z + (double)xb.w * wb.w;
            #pragma unroll
            for (int off = 32; off > 0; off >>= 1) s += __shfl_xor(s, off);
            dots[t] = s;
        }
        if (lane == 0) {
            double scd = (double)ga[d] / sqrt((double)va[d] + 1e-5);
            double v = 0.0;
            #pragma unroll
            for (int t = 0; t < 4; ++t) {
                double yb = (dots[t] + (double)bi[d] - (double)mu[d]) * scd + (double)be[d];
                v = v + (yb - v) * 0.5;
                u64* wp = &packed[pidx(branch, t, m >> 9, m & 511, d >> 6)];
                u64 msk = 1ull << (d & 63);
                if (v >= 1.0) { atomicOr(wp, msk); v = 0.0; }
                else          { atomicAnd(wp, ~msk); }
            }
        }
    }
}

// ---------------- K2a: KV[e][d] popcount per (t,b,h) -> f16 fragment-major ----------------
__global__ __launch_bounds__(256) void k_kv(const u64* __restrict__ packed, short* __restrict__ kvf,
                                            u32* __restrict__ flags2z)
{
    __shared__ u64 km[512], vm[512];
    __shared__ u64 kc[64][8], vc[64][8];
    const int bx = blockIdx.x;
    const int t = bx >> 6, b = (bx >> 3) & 7, h = bx & 7;
    const int tid = threadIdx.x;
    if (flags2z && bx == 0 && tid == 0) flags2z[0] = 0;

    #pragma unroll
    for (int i = 0; i < 2; ++i) {
        int n = tid + i * 256;
        km[n] = packed[pidx(1, t, b, n, h)];
        vm[n] = packed[pidx(2, t, b, n, h)];
    }
    __syncthreads();
    #pragma unroll
    for (int i = 0; i < 2; ++i) {
        int f = tid + i * 256;
        int e = f >> 3, w = f & 7;
        u64 kr = 0ull, vr = 0ull;
        for (int j = 0; j < 64; ++j) {
            kr |= ((km[w * 64 + j] >> e) & 1ull) << j;
            vr |= ((vm[w * 64 + j] >> e) & 1ull) << j;
        }
        kc[e][w] = kr; vc[e][w] = vr;
    }
    __syncthreads();
    short* out = kvf + (size_t)bx * 4096;
    #pragma unroll
    for (int i = 0; i < 16; ++i) {
        int f = tid + i * 256;
        int j = f & 7, lane = (f >> 3) & 63, ks = (f >> 9) & 1, dsub = f >> 10;
        int e = ks * 32 + ((lane >> 4) & 3) * 8 + j;
        int d = dsub * 16 + (lane & 15);
        int s = 0;
        #pragma unroll
        for (int w = 0; w < 8; ++w) s += __popcll(kc[e][w] & vc[d][w]);
        _Float16 hv = (_Float16)(float)s;
        out[f] = *(short*)&hv;
    }
}

// ---------------- K2b: f16 MFMA q@KV + exact LIF(thr=0.5) -> s2 bits ----------------
__global__ __launch_bounds__(256, 1) void k_attn(const u64* __restrict__ packed,
                                                 const short* __restrict__ kvf,
                                                 u16* __restrict__ s2)
{
    const int bx = blockIdx.x;
    const int b = bx >> 5, h = (bx >> 2) & 7, nt = bx & 3;
    const int tid = threadIdx.x;
    const int wave = tid >> 6, lane = tid & 63;
    const int l15 = lane & 15, g = lane >> 4;
    const int n0 = nt * 128 + wave * 32;

    float v[2][4][4];
    #pragma unroll
    for (int ms = 0; ms < 2; ++ms)
        #pragma unroll
        for (int ds = 0; ds < 4; ++ds)
            #pragma unroll
            for (int r = 0; r < 4; ++r) v[ms][ds][r] = 0.f;

    for (int t = 0; t < 4; ++t) {
        short8 bf[4][2];
        const size_t kvbase = (size_t)(((t * 8 + b) * 8 + h)) * 4096;
        #pragma unroll
        for (int ds = 0; ds < 4; ++ds)
            #pragma unroll
            for (int ks = 0; ks < 2; ++ks)
                bf[ds][ks] = *(const short8*)&kvf[kvbase + (size_t)((ds * 2 + ks) * 64 + lane) * 8];
        u64 qm[2];
        #pragma unroll
        for (int ms = 0; ms < 2; ++ms)
            qm[ms] = packed[pidx(0, t, b, n0 + ms * 16 + l15, h)];

        f32x4 acc[2][4];
        #pragma unroll
        for (int ms = 0; ms < 2; ++ms)
            #pragma unroll
            for (int ds = 0; ds < 4; ++ds) acc[ms][ds] = (f32x4)0.0f;

        #pragma unroll
        for (int ks = 0; ks < 2; ++ks)
            #pragma unroll
            for (int ms = 0; ms < 2; ++ms) {
                u32 byte = (u32)(qm[ms] >> ((ks * 4 + g) * 8)) & 0xFFu;
                short8 af;
                #pragma unroll
                for (int j = 0; j < 8; ++j) af[j] = ((byte >> j) & 1u) ? (short)0x3C00 : (short)0;
                half8 av = *(half8*)&af;
                #pragma unroll
                for (int ds = 0; ds < 4; ++ds)
                    acc[ms][ds] = __builtin_amdgcn_mfma_f32_16x16x32_f16(av, *(half8*)&bf[ds][ks],
                                                                         acc[ms][ds], 0, 0, 0);
            }
        #pragma unroll
        for (int ms = 0; ms < 2; ++ms)
            #pragma unroll
            for (int ds = 0; ds < 4; ++ds)
                #pragma unroll
                for (int r = 0; r < 4; ++r) {
                    float y = acc[ms][ds][r] * 0.125f;
                    float vv = v[ms][ds][r];
                    vv = vv + (y - vv) * 0.5f;
                    bool s = vv >= 0.5f;
                    u64 bal = __ballot(s);
                    if (s) vv = 0.f;
                    v[ms][ds][r] = vv;
                    if (l15 == 0) {
                        int n = n0 + ms * 16 + g * 4 + r;
                        s2[((size_t)(t * 8 + b) * 512 + n) * 32 + h * 4 + ds] =
                            (u16)((bal >> (g * 16)) & 0xFFFFull);
                    }
                }
    }
}

// ---------------- repair2: fp64 recompute of flagged p-branch chains ----------------
__global__ __launch_bounds__(256) void k_repair2(
    const u16* __restrict__ s2,
    const float* __restrict__ pw, const float* __restrict__ pbi,
    const float* __restrict__ pga, const float* __restrict__ pbe,
    const float* __restrict__ pmu, const float* __restrict__ pva,
    const u32* __restrict__ flags, float* __restrict__ out)
{
    u32 n = flags[0]; if (n > CAP2) n = CAP2;
    int gw = (blockIdx.x * 256 + threadIdx.x) >> 6;
    int lane = threadIdx.x & 63;
    int nw = gridDim.x * 4;
    for (u32 i = gw; i < n; i += nw) {
        u32 e = flags[4 + i];
        int m = (e >> 9) & 4095, d = e & 511;
        const float* wr = pw + (size_t)d * 512 + lane * 8;
        float4 wa = *(const float4*)wr, wb = *(const float4*)(wr + 4);
        float we[8] = {wa.x, wa.y, wa.z, wa.w, wb.x, wb.y, wb.z, wb.w};
        double dots[4];
        #pragma unroll
        for (int t = 0; t < 4; ++t) {
            u16 wd = s2[((size_t)(t * 4096 + m)) * 32 + (lane >> 1)];
            int sh = (lane & 1) * 8;
            double s = 0.0;
            #pragma unroll
            for (int j = 0; j < 8; ++j)
                if ((wd >> (sh + j)) & 1) s += (double)we[j];
            #pragma unroll
            for (int off = 32; off > 0; off >>= 1) s += __shfl_xor(s, off);
            dots[t] = s;
        }
        if (lane == 0) {
            double scd = (double)pga[d] / sqrt((double)pva[d] + 1e-5);
            double v = 0.0;
            #pragma unroll
            for (int t = 0; t < 4; ++t) {
                double yb = (dots[t] + (double)pbi[d] - (double)pmu[d]) * scd + (double)pbe[d];
                v = v + (yb - v) * 0.5;
                bool s = v >= 1.0;
                out[((size_t)(t * 4096 + m)) * 512 + d] = s ? 1.0f : 0.0f;
                if (s) v = 0.0;
            }
        }
    }
}

extern "C" void kernel_launch(void* const* d_in, const int* in_sizes, int n_in,
                              void* d_out, int out_size, void* d_ws, size_t ws_size,
                              hipStream_t stream) {
    const float* x   = (const float*)d_in[0];
    const float* qw  = (const float*)d_in[1];
    const float* qb  = (const float*)d_in[2];
    const float* qga = (const float*)d_in[3];
    const float* qbe = (const float*)d_in[4];
    const float* qmu = (const float*)d_in[5];
    const float* qva = (const float*)d_in[6];
    const float* kw  = (const float*)d_in[7];
    const float* kb  = (const float*)d_in[8];
    const float* kga = (const float*)d_in[9];
    const float* kbe = (const float*)d_in[10];
    const float* kmu = (const float*)d_in[11];
    const float* kva = (const float*)d_in[12];
    const float* vw  = (const float*)d_in[13];
    const float* vb  = (const float*)d_in[14];
    const float* vga = (const float*)d_in[15];
    const float* vbe = (const float*)d_in[16];
    const float* vmu = (const float*)d_in[17];
    const float* vva_= (const float*)d_in[18];
    const float* pw  = (const float*)d_in[19];
    const float* pb  = (const float*)d_in[20];
    const float* pga = (const float*)d_in[21];
    const float* pbe = (const float*)d_in[22];
    const float* pmu = (const float*)d_in[23];
    const float* pva = (const float*)d_in[24];

    char* W = (char*)d_ws;
    u64*  packed = (u64*)W;                          // [0, 3M)
    short* kvf   = (short*)(W + (3u << 20));         // [3M, 5M)
    u16*  s2     = (u16*)(W + (5u << 20));           // [5M, 6M)
    short* wfh   = (short*)(W + (6u << 20));         // [6M, 8M)
    short* wfl   = (short*)(W + (8u << 20));         // [8M, 10M)
    short* xfh   = (short*)(W + (10u << 20));        // [10M, 26M)
    short* xfl   = (short*)(W + (26u << 20));        // [26M, 42M)
    u32*  flags1 = (u32*)(W + (3u << 20));           // transient [3M,6M), dead after repair1
    u32*  flags2b= (u32*)(W + (26u << 20));          // big path: xfl region, dead after k_branch
    u32*  flags2s= (u32*)W;                          // small path: packed region, dead after k_attn

    const bool big_ws = ws_size >= (44ull << 20);

    if (big_ws) {
        k_split_xw<<<4608, 256, 0, stream>>>(x, qw, kw, vw, pw, wfh, wfl, xfh, xfl, flags1);
        k_branch_p2<<<dim3(64, 12), 512, 0, stream>>>(
            xfh, xfl, wfh, wfl,
            qb, qga, qbe, qmu, qva,
            kb, kga, kbe, kmu, kva,
            vb, vga, vbe, vmu, vva_,
            packed, flags1);
    } else {
        k_split_xw<<<512, 256, 0, stream>>>(x, qw, kw, vw, pw, wfh, wfl, xfh, xfl, flags1);
        k_branch_v4<<<dim3(64, 12), 512, 0, stream>>>(
            x, wfh, wfl,
            qb, qga, qbe, qmu, qva,
            kb, kga, kbe, kmu, kva,
            vb, vga, vbe, vmu, vva_,
            packed, flags1);
    }
    k_repair1<<<256, 256, 0, stream>>>(
        x,
        qw, qb, qga, qbe, qmu, qva,
        kw, kb, kga, kbe, kmu, kva,
        vw, vb, vga, vbe, vmu, vva_,
        flags1, packed);
    k_kv<<<256, 256, 0, stream>>>(packed, kvf, big_ws ? flags2b : (u32*)nullptr);
    k_attn<<<256, 256, 0, stream>>>(packed, kvf, s2);
    if (big_ws) {
        k_pbranch_f2<<<dim3(64, 8), 512, 0, stream>>>(
            s2, wfh, wfl, pb, pga, pbe, pmu, pva, (float*)d_out, flags2b);
        k_repair2<<<128, 256, 0, stream>>>(
            s2, pw, pb, pga, pbe, pmu, pva, flags2b, (float*)d_out);
    } else {
        k_zero<<<1, 64, 0, stream>>>(flags2s);
        k_pbranch_f2<<<dim3(64, 8), 512, 0, stream>>>(
            s2, wfh, wfl, pb, pga, pbe, pmu, pva, (float*)d_out, flags2s);
        k_repair2<<<128, 256, 0, stream>>>(
            s2, pw, pb, pga, pbe, pmu, pva, flags2s, (float*)d_out);
    }
}

// Round 11
// 203.946 us; speedup vs baseline: 1.0690x; 1.0690x over previous
//
#include <hip/hip_runtime.h>
#include <cstdint>

typedef unsigned long long u64;
typedef unsigned int u32;
typedef unsigned short u16;

typedef __attribute__((ext_vector_type(8))) short short8;
typedef __attribute__((ext_vector_type(4))) float f32x4;
typedef _Float16 half8 __attribute__((ext_vector_type(8)));

#define EPSF 1e-3f
#define CAP1 780000u
#define CAP2 780000u

__device__ __forceinline__ int pidx(int br, int t, int b, int n, int h) {
    return (((br * 4 + t) * 8 + b) * 512 + n) * 8 + h;
}

// truncation split: x = hi + lo + eps, |eps| <= |x|*2^-16
__device__ __forceinline__ void split1(float f, short& h, short& l) {
    u32 u = __float_as_uint(f);
    u32 hb = u & 0xFFFF0000u;
    float r = f - __uint_as_float(hb);
    h = (short)(hb >> 16);
    l = (short)(__float_as_uint(r) >> 16);
}

// async global->LDS, 16B per lane; dest = wave-uniform base + lane*16
__device__ __forceinline__ void gload_lds16(const void* g, void* lds_base, int lane) {
#if __has_builtin(__builtin_amdgcn_global_load_lds)
    __builtin_amdgcn_global_load_lds(
        (const __attribute__((address_space(1))) unsigned int*)g,
        (__attribute__((address_space(3))) unsigned int*)lds_base, 16, 0, 0);
#else
    ((short8*)lds_base)[lane] = *(const short8*)g;
#endif
}

__global__ void k_zero(u32* p) {
    if (threadIdx.x == 0 && blockIdx.x == 0) *p = 0;
}

// ---------------- merged pre-split: W (blocks 0..511) + x (blocks 512..4607) ----------------
__global__ __launch_bounds__(256) void k_split_xw(
    const float* __restrict__ x,
    const float* __restrict__ qw, const float* __restrict__ kw,
    const float* __restrict__ vw, const float* __restrict__ pw,
    short* __restrict__ wfh, short* __restrict__ wfl,
    short* __restrict__ xfh, short* __restrict__ xfl, u32* __restrict__ flags1)
{
    const int bid = blockIdx.x;
    const int tid = threadIdx.x;
    if (bid < 512) {
        int idx = bid * 256 + tid;                // [0, 131072)
        if (idx == 0) flags1[0] = 0;
        int lane = idx & 63;
        int kb = (idx >> 6) & 15;
        int dt = (idx >> 10) & 31;
        int mat = idx >> 15;
        const float* W = mat == 0 ? qw : (mat == 1 ? kw : (mat == 2 ? vw : pw));
        int d = dt * 16 + (lane & 15);
        int k = kb * 32 + ((lane >> 4) & 3) * 8;
        const float* p = W + (size_t)d * 512 + k;
        float4 a = *(const float4*)p, b = *(const float4*)(p + 4);
        float fv[8] = {a.x, a.y, a.z, a.w, b.x, b.y, b.z, b.w};
        short8 vh, vl;
        #pragma unroll
        for (int j = 0; j < 8; ++j) { short hh, ll; split1(fv[j], hh, ll); vh[j] = hh; vl[j] = ll; }
        *(short8*)&wfh[(size_t)idx * 8] = vh;
        *(short8*)&wfl[(size_t)idx * 8] = vl;
    } else {
        int idx = (bid - 512) * 256 + tid;        // [0, 1048576)
        int lane = idx & 63;
        int msub = (idx >> 6) & 3;
        int kb = (idx >> 8) & 15;
        int t = (idx >> 12) & 3;
        int mt = idx >> 14;                       // [0, 64)
        int l15 = lane & 15, g = lane >> 4;
        int row = mt * 64 + msub * 16 + l15;
        int col = kb * 32 + g * 8;
        const float* p = &x[((size_t)(t * 4096 + row)) * 512 + col];
        float4 a = *(const float4*)p, b = *(const float4*)(p + 4);
        float fv[8] = {a.x, a.y, a.z, a.w, b.x, b.y, b.z, b.w};
        short8 vh, vl;
        #pragma unroll
        for (int j = 0; j < 8; ++j) { short hh, ll; split1(fv[j], hh, ll); vh[j] = hh; vl[j] = ll; }
        *(short8*)&xfh[(size_t)idx * 8] = vh;
        *(short8*)&xfl[(size_t)idx * 8] = vl;
    }
}

// ---------------- K1 p2: depth-2 counted-vmcnt pipelined 3-branch bf16x3 MFMA GEMM -------------
// grid (64, 12), 512 threads (8 waves, 32m x 32d each); A dbuf LDS 64KB, B ping-pong regs
// (512,4): R8-proven config — fastest measured (129 us) despite minor scratch spill
__global__ __launch_bounds__(512, 4) void k_branch_p2(
    const short* __restrict__ xfh, const short* __restrict__ xfl,
    const short* __restrict__ wfh, const short* __restrict__ wfl,
    const float* __restrict__ bi0, const float* __restrict__ ga0,
    const float* __restrict__ be0, const float* __restrict__ mu0, const float* __restrict__ va0,
    const float* __restrict__ bi1, const float* __restrict__ ga1,
    const float* __restrict__ be1, const float* __restrict__ mu1, const float* __restrict__ va1,
    const float* __restrict__ bi2, const float* __restrict__ ga2,
    const float* __restrict__ be2, const float* __restrict__ mu2, const float* __restrict__ va2,
    u64* __restrict__ packed, u32* __restrict__ flags)
{
    __shared__ __align__(16) short Ah[2][8192];   // 2 x 16KB
    __shared__ __align__(16) short Al[2][8192];   // 2 x 16KB

    const int tid = threadIdx.x;
    const int wave = tid >> 6, lane = tid & 63;
    const int l15 = lane & 15, g = lane >> 4;
    const int mhalf = wave & 1, dquad = wave >> 1;
    const int ta = wave >> 1, pr = wave & 1;      // A-staging role
    const int mt = blockIdx.x;
    const int m0 = mt * 64;
    const int gy = blockIdx.y;
    const int branch = gy >> 2;
    const int hp = gy & 3;
    const int d0 = hp * 128;

    const float *bp = bi0, *gp = ga0, *bep = be0, *mup = mu0, *vap = va0;
    if (branch == 1) { bp = bi1; gp = ga1; bep = be1; mup = mu1; vap = va1; }
    if (branch == 2) { bp = bi2; gp = ga2; bep = be2; mup = mu2; vap = va2; }

    f32x4 acc[4][2][2];
    #pragma unroll
    for (int t = 0; t < 4; ++t)
        #pragma unroll
        for (int ms = 0; ms < 2; ++ms)
            #pragma unroll
            for (int ds = 0; ds < 2; ++ds) acc[t][ms][ds] = (f32x4)0.0f;

    auto stageA = [&](int kb, short* AhB, short* AlB) {
        const size_t abase = ((size_t)((mt * 4 + ta) * 16 + kb) * 4) * 512;
        #pragma unroll
        for (int s = 0; s < 2; ++s) {
            int msub = pr * 2 + s;
            gload_lds16(&xfh[abase + (size_t)msub * 512 + lane * 8], &AhB[(ta * 4 + msub) * 512], lane);
            gload_lds16(&xfl[abase + (size_t)msub * 512 + lane * 8], &AlB[(ta * 4 + msub) * 512], lane);
        }
    };
    auto loadB = [&](int kb, short8* b) {
        #pragma unroll
        for (int ds = 0; ds < 2; ++ds) {
            const size_t src = ((size_t)((branch * 32 + hp * 8 + dquad * 2 + ds) * 16 + kb) * 64 + lane) * 8;
            b[ds * 2 + 0] = *(const short8*)&wfh[src];
            b[ds * 2 + 1] = *(const short8*)&wfl[src];
        }
    };
    auto compute = [&](const short* AhB, const short* AlB, const short8* b) {
        #pragma unroll
        for (int t = 0; t < 4; ++t)
            #pragma unroll
            for (int ms = 0; ms < 2; ++ms) {
                int ch = ((t * 4 + mhalf * 2 + ms) * 64 + lane) * 8;
                short8 ah = *(const short8*)&AhB[ch];
                short8 al = *(const short8*)&AlB[ch];
                #pragma unroll
                for (int ds = 0; ds < 2; ++ds) {
                    f32x4 c = acc[t][ms][ds];
                    c = __builtin_amdgcn_mfma_f32_16x16x32_bf16(ah, b[ds * 2 + 0], c, 0, 0, 0);
                    c = __builtin_amdgcn_mfma_f32_16x16x32_bf16(ah, b[ds * 2 + 1], c, 0, 0, 0);
                    c = __builtin_amdgcn_mfma_f32_16x16x32_bf16(al, b[ds * 2 + 0], c, 0, 0, 0);
                    acc[t][ms][ds] = c;
                }
            }
    };

    short8 bA[4], bB[4];
    // prologue: queue = [s0(4)] [b0(4)] [s1(4)] -> vmcnt(8) completes s0 only
    stageA(0, Ah[0], Al[0]);
    loadB(0, bA);
    stageA(1, Ah[1], Al[1]);
    asm volatile("s_waitcnt vmcnt(8)" ::: "memory");
    __builtin_amdgcn_s_barrier();

    for (int kb = 0; kb < 14; kb += 2) {
        // even: compute kb from buf0/bA; stage kb+2 -> buf0
        loadB(kb + 1, bB);
        compute(Ah[0], Al[0], bA);                 // bA regs auto-waited (oldest)
        asm volatile("s_waitcnt lgkmcnt(0)" ::: "memory");
        __builtin_amdgcn_s_barrier();              // all waves done reading buf0
        stageA(kb + 2, Ah[0], Al[0]);
        asm volatile("s_waitcnt vmcnt(8)" ::: "memory");   // completes stage(kb+1)
        __builtin_amdgcn_s_barrier();              // buf1 (kb+1) now valid for all
        // odd: compute kb+1 from buf1/bB; stage kb+3 -> buf1
        loadB(kb + 2, bA);
        compute(Ah[1], Al[1], bB);
        asm volatile("s_waitcnt lgkmcnt(0)" ::: "memory");
        __builtin_amdgcn_s_barrier();
        stageA(kb + 3, Ah[1], Al[1]);
        asm volatile("s_waitcnt vmcnt(8)" ::: "memory");   // completes stage(kb+2)
        __builtin_amdgcn_s_barrier();
    }
    // kb = 14
    loadB(15, bB);
    compute(Ah[0], Al[0], bA);
    asm volatile("s_waitcnt lgkmcnt(0)" ::: "memory");
    __builtin_amdgcn_s_barrier();
    asm volatile("s_waitcnt vmcnt(4)" ::: "memory");       // completes stage(15)
    __builtin_amdgcn_s_barrier();
    // kb = 15
    compute(Ah[1], Al[1], bB);

    float scv[2], muv[2], bev[2], biv[2];
    #pragma unroll
    for (int ds = 0; ds < 2; ++ds) {
        int d = d0 + dquad * 32 + ds * 16 + l15;
        scv[ds] = gp[d] / sqrtf(vap[d] + 1e-5f);
        muv[ds] = mup[d]; bev[ds] = bep[d]; biv[ds] = bp[d];
    }

    __syncthreads();
    u64* Pk = (u64*)Ah;                           // 4KB alias (Ah dead now)
    Pk[tid] = 0ull;
    __syncthreads();

    const int word = dquad >> 1;
    const int shbase = (dquad & 1) * 32;
    #pragma unroll
    for (int ms = 0; ms < 2; ++ms)
        #pragma unroll
        for (int ds = 0; ds < 2; ++ds)
            #pragma unroll
            for (int r = 0; r < 4; ++r) {
                int rowl = mhalf * 32 + ms * 16 + g * 4 + r;
                float v = 0.f, mm = 1e9f;
                #pragma unroll
                for (int t = 0; t < 4; ++t) {
                    float yb = (acc[t][ms][ds][r] + biv[ds] - muv[ds]) * scv[ds] + bev[ds];
                    v = v + (yb - v) * 0.5f;
                    mm = fminf(mm, fabsf(v - 1.0f));
                    bool s = v >= 1.0f;
                    u64 bal = __ballot(s);
                    if (s) v = 0.f;
                    if (l15 == 0) {
                        u64 b16 = (bal >> (g * 16)) & 0xFFFFull;
                        if (b16) atomicOr(&Pk[(t * 64 + rowl) * 2 + word], b16 << (shbase + ds * 16));
                    }
                }
                if (mm < EPSF) {
                    u32 ix = atomicAdd(flags, 1u);
                    if (ix < CAP1)
                        flags[4 + ix] = ((u32)branch << 21) | ((u32)(m0 + rowl) << 9)
                                      | (u32)(d0 + dquad * 32 + ds * 16 + l15);
                }
            }
    __syncthreads();
    {
        int t = tid >> 7, rem = tid & 127, row = rem >> 1, w = rem & 1;
        int m = m0 + row;
        packed[pidx(branch, t, m >> 9, m & 511, hp * 2 + w)] = Pk[(t * 64 + row) * 2 + w];
    }
}

// ---------------- K3 f2: p-branch MFMA with in-kernel s2 expand, 1 barrier/K-step ---------
// grid (64, 8), 512 threads (8 waves, 32m x 16d each); A dbuf 32KB (spikes exact, no lo)
__global__ __launch_bounds__(512, 4) void k_pbranch_f2(
    const u16* __restrict__ s2,
    const short* __restrict__ wfh, const short* __restrict__ wfl,
    const float* __restrict__ pbi, const float* __restrict__ pga,
    const float* __restrict__ pbe, const float* __restrict__ pmu, const float* __restrict__ pva,
    float* __restrict__ out, u32* __restrict__ flags)
{
    __shared__ __align__(16) short Ab[2][8192];   // 2 x 16KB

    const int tid = threadIdx.x;
    const int wave = tid >> 6, lane = tid & 63;
    const int l15 = lane & 15, g = lane >> 4;
    const int mhalf = wave & 1, dq = wave >> 1;
    const int m0 = blockIdx.x * 64;
    const int d0 = blockIdx.y * 64;

    // expand role
    const int et = tid >> 7, em = (tid >> 1) & 63, echh = tid & 1;
    const u32* s2row = (const u32*)&s2[((size_t)(et * 4096 + m0 + em)) * 32];

    f32x4 acc[4][2];
    #pragma unroll
    for (int t = 0; t < 4; ++t)
        #pragma unroll
        for (int ms = 0; ms < 2; ++ms) acc[t][ms] = (f32x4)0.0f;

    auto loadB = [&](int kb, short8* b) {
        const size_t src = ((size_t)((96 + (d0 >> 4) + dq) * 16 + kb) * 64 + lane) * 8;
        b[0] = *(const short8*)&wfh[src];
        b[1] = *(const short8*)&wfl[src];
    };
    auto expand = [&](u32 bits, short* buf) {
        #pragma unroll
        for (int cc = 0; cc < 2; ++cc) {
            int c = echh * 2 + cc;
            short8 vv;
            #pragma unroll
            for (int j = 0; j < 8; ++j)
                vv[j] = ((bits >> (c * 8 + j)) & 1u) ? (short)0x3F80 : (short)0;
            int ch = (et * 4 + (em >> 4)) * 64 + (((em & 15) ^ (c << 2)) + c * 16);
            *(short8*)&buf[ch * 8] = vv;
        }
    };
    const int chp = ((l15 ^ (g << 2)) + g * 16);
    auto compute = [&](const short* buf, const short8* b) {
        #pragma unroll
        for (int t = 0; t < 4; ++t)
            #pragma unroll
            for (int ms = 0; ms < 2; ++ms) {
                short8 ah = *(const short8*)&buf[((t * 4 + mhalf * 2 + ms) * 64 + chp) * 8];
                f32x4 c = acc[t][ms];
                c = __builtin_amdgcn_mfma_f32_16x16x32_bf16(ah, b[0], c, 0, 0, 0);
                c = __builtin_amdgcn_mfma_f32_16x16x32_bf16(ah, b[1], c, 0, 0, 0);
                acc[t][ms] = c;
            }
    };

    short8 bA[2], bB[2];
    u32 sA = s2row[0];                            // bits for kb=0
    u32 sB = s2row[1];                            // bits for kb=1
    loadB(0, bA);
    loadB(1, bB);
    expand(sA, Ab[0]);
    __syncthreads();

    for (int kb = 0; kb < 16; kb += 2) {
        // even: compute(kb) on Ab[0]/bA; expand(kb+1) -> Ab[1]
        if (kb < 14) sA = s2row[kb + 2];
        expand(sB, Ab[1]);
        compute(Ab[0], bA);
        if (kb < 14) loadB(kb + 2, bA);
        __syncthreads();
        // odd: compute(kb+1) on Ab[1]/bB; expand(kb+2) -> Ab[0]
        if (kb < 14) {
            sB = s2row[kb + 3];
            expand(sA, Ab[0]);
        }
        compute(Ab[1], bB);
        if (kb < 14) loadB(kb + 3, bB);
        __syncthreads();
    }

    const int d = d0 + dq * 16 + l15;
    const float scv = pga[d] / sqrtf(pva[d] + 1e-5f);
    const float muv = pmu[d], bev = pbe[d], biv = pbi[d];

    #pragma unroll
    for (int ms = 0; ms < 2; ++ms)
        #pragma unroll
        for (int r = 0; r < 4; ++r) {
            int row = m0 + mhalf * 32 + ms * 16 + g * 4 + r;
            float v = 0.f, mm = 1e9f;
            #pragma unroll
            for (int t = 0; t < 4; ++t) {
                float yb = (acc[t][ms][r] + biv - muv) * scv + bev;
                v = v + (yb - v) * 0.5f;
                mm = fminf(mm, fabsf(v - 1.0f));
                bool s = v >= 1.0f;
                out[((size_t)(t * 4096 + row)) * 512 + d] = s ? 1.0f : 0.0f;
                if (s) v = 0.f;
            }
            if (mm < EPSF) {
                u32 ix = atomicAdd(flags, 1u);
                if (ix < CAP2) flags[4 + ix] = ((u32)row << 9) | (u32)d;
            }
        }
}

// ---------------- V4 fallback kernels (in-kernel split), used when ws is small ----------------
__global__ __launch_bounds__(512, 2) void k_branch_v4(
    const float* __restrict__ x,
    const short* __restrict__ wfh, const short* __restrict__ wfl,
    const float* __restrict__ bi0, const float* __restrict__ ga0,
    const float* __restrict__ be0, const float* __restrict__ mu0, const float* __restrict__ va0,
    const float* __restrict__ bi1, const float* __restrict__ ga1,
    const float* __restrict__ be1, const float* __restrict__ mu1, const float* __restrict__ va1,
    const float* __restrict__ bi2, const float* __restrict__ ga2,
    const float* __restrict__ be2, const float* __restrict__ mu2, const float* __restrict__ va2,
    u64* __restrict__ packed, u32* __restrict__ flags)
{
    __shared__ __align__(16) short Ah[4 * 4 * 64 * 8];
    __shared__ __align__(16) short Al[4 * 4 * 64 * 8];
    __shared__ __align__(16) short Bh[8 * 64 * 8];
    __shared__ __align__(16) short Bl[8 * 64 * 8];

    const int tid = threadIdx.x;
    const int wave = tid >> 6, lane = tid & 63;
    const int l15 = lane & 15, g = lane >> 4;
    const int mhalf = wave & 1, dquad = wave >> 1;
    const int m0 = blockIdx.x * 64;
    const int gy = blockIdx.y;
    const int branch = gy >> 2;
    const int hp = gy & 3;
    const int d0 = hp * 128;

    const float *bp = bi0, *gp = ga0, *bep = be0, *mup = mu0, *vap = va0;
    if (branch == 1) { bp = bi1; gp = ga1; bep = be1; mup = mu1; vap = va1; }
    if (branch == 2) { bp = bi2; gp = ga2; bep = be2; mup = mu2; vap = va2; }

    f32x4 acc[4][2][2];
    #pragma unroll
    for (int t = 0; t < 4; ++t)
        #pragma unroll
        for (int ms = 0; ms < 2; ++ms)
            #pragma unroll
            for (int ds = 0; ds < 2; ++ds) acc[t][ms][ds] = (f32x4)0.0f;

    for (int k0 = 0; k0 < 512; k0 += 32) {
        const int kb = k0 >> 5;
        __syncthreads();
        {
            const size_t src = ((size_t)((branch * 32 + hp * 8 + wave) * 16 + kb) * 64 + lane) * 8;
            gload_lds16(&wfh[src], &Bh[wave * 512], lane);
            gload_lds16(&wfl[src], &Bl[wave * 512], lane);
        }
        #pragma unroll
        for (int i = 0; i < 2; ++i) {
            int f = tid + i * 512;
            int c = f & 3, m = (f >> 2) & 63, t = f >> 8;
            const float* xp = &x[(size_t)(t * 4096 + m0 + m) * 512 + k0 + c * 8];
            float4 a = *(const float4*)xp, b = *(const float4*)(xp + 4);
            float fv[8] = {a.x, a.y, a.z, a.w, b.x, b.y, b.z, b.w};
            short8 vh, vl;
            #pragma unroll
            for (int j = 0; j < 8; ++j) { short hh, ll; split1(fv[j], hh, ll); vh[j] = hh; vl[j] = ll; }
            int ch = (t * 4 + (m >> 4)) * 64 + (((m & 15) ^ (c << 2)) + c * 16);
            *(short8*)&Ah[ch * 8] = vh;
            *(short8*)&Al[ch * 8] = vl;
        }
        __syncthreads();

        short8 bh[2], bl[2];
        #pragma unroll
        for (int ds = 0; ds < 2; ++ds) {
            int chunk = (dquad * 2 + ds) * 64 + lane;
            bh[ds] = *(short8*)&Bh[chunk * 8];
            bl[ds] = *(short8*)&Bl[chunk * 8];
        }
        const int chp = ((l15 ^ (g << 2)) + g * 16);
        #pragma unroll
        for (int t = 0; t < 4; ++t)
            #pragma unroll
            for (int ms = 0; ms < 2; ++ms) {
                int ch = ((t * 4 + mhalf * 2 + ms) * 64 + chp) * 8;
                short8 ah = *(short8*)&Ah[ch];
                short8 al = *(short8*)&Al[ch];
                #pragma unroll
                for (int ds = 0; ds < 2; ++ds) {
                    f32x4 c = acc[t][ms][ds];
                    c = __builtin_amdgcn_mfma_f32_16x16x32_bf16(ah, bh[ds], c, 0, 0, 0);
                    c = __builtin_amdgcn_mfma_f32_16x16x32_bf16(ah, bl[ds], c, 0, 0, 0);
                    c = __builtin_amdgcn_mfma_f32_16x16x32_bf16(al, bh[ds], c, 0, 0, 0);
                    acc[t][ms][ds] = c;
                }
            }
    }

    float scv[2], muv[2], bev[2], biv[2];
    #pragma unroll
    for (int ds = 0; ds < 2; ++ds) {
        int d = d0 + dquad * 32 + ds * 16 + l15;
        scv[ds] = gp[d] / sqrtf(vap[d] + 1e-5f);
        muv[ds] = mup[d]; bev[ds] = bep[d]; biv[ds] = bp[d];
    }

    __syncthreads();
    u64* Pk = (u64*)Bh;
    Pk[tid] = 0ull;
    __syncthreads();

    const int word = dquad >> 1;
    const int shbase = (dquad & 1) * 32;
    #pragma unroll
    for (int ms = 0; ms < 2; ++ms)
        #pragma unroll
        for (int ds = 0; ds < 2; ++ds)
            #pragma unroll
            for (int r = 0; r < 4; ++r) {
                int rowl = mhalf * 32 + ms * 16 + g * 4 + r;
                float v = 0.f, mm = 1e9f;
                #pragma unroll
                for (int t = 0; t < 4; ++t) {
                    float yb = (acc[t][ms][ds][r] + biv[ds] - muv[ds]) * scv[ds] + bev[ds];
                    v = v + (yb - v) * 0.5f;
                    mm = fminf(mm, fabsf(v - 1.0f));
                    bool s = v >= 1.0f;
                    u64 bal = __ballot(s);
                    if (s) v = 0.f;
                    if (l15 == 0) {
                        u64 b16 = (bal >> (g * 16)) & 0xFFFFull;
                        if (b16) atomicOr(&Pk[(t * 64 + rowl) * 2 + word], b16 << (shbase + ds * 16));
                    }
                }
                if (mm < EPSF) {
                    u32 ix = atomicAdd(flags, 1u);
                    if (ix < CAP1)
                        flags[4 + ix] = ((u32)branch << 21) | ((u32)(m0 + rowl) << 9)
                                      | (u32)(d0 + dquad * 32 + ds * 16 + l15);
                }
            }
    __syncthreads();
    {
        int t = tid >> 7, rem = tid & 127, row = rem >> 1, w = rem & 1;
        int m = m0 + row;
        packed[pidx(branch, t, m >> 9, m & 511, hp * 2 + w)] = Pk[(t * 64 + row) * 2 + w];
    }
}

// ---------------- repair1: fp64 recompute of flagged (branch,m,d) chains ----------------
__global__ __launch_bounds__(256) void k_repair1(
    const float* __restrict__ x,
    const float* __restrict__ w0, const float* __restrict__ bi0,
    const float* __restrict__ ga0, const float* __restrict__ be0,
    const float* __restrict__ mu0, const float* __restrict__ va0,
    const float* __restrict__ w1, const float* __restrict__ bi1,
    const float* __restrict__ ga1, const float* __restrict__ be1,
    const float* __restrict__ mu1, const float* __restrict__ va1,
    const float* __restrict__ w2, const float* __restrict__ bi2,
    const float* __restrict__ ga2, const float* __restrict__ be2,
    const float* __restrict__ mu2, const float* __restrict__ va2,
    const u32* __restrict__ flags, u64* __restrict__ packed)
{
    u32 n = flags[0]; if (n > CAP1) n = CAP1;
    int gw = (blockIdx.x * 256 + threadIdx.x) >> 6;
    int lane = threadIdx.x & 63;
    int nw = gridDim.x * 4;
    for (u32 i = gw; i < n; i += nw) {
        u32 e = flags[4 + i];
        int branch = e >> 21, m = (e >> 9) & 4095, d = e & 511;
        const float* W  = branch == 0 ? w0  : (branch == 1 ? w1  : w2);
        const float* bi = branch == 0 ? bi0 : (branch == 1 ? bi1 : bi2);
        const float* ga = branch == 0 ? ga0 : (branch == 1 ? ga1 : ga2);
        const float* be = branch == 0 ? be0 : (branch == 1 ? be1 : be2);
        const float* mu = branch == 0 ? mu0 : (branch == 1 ? mu1 : mu2);
        const float* va = branch == 0 ? va0 : (branch == 1 ? va1 : va2);
        const float* wr = W + (size_t)d * 512 + lane * 8;
        float4 wa = *(const float4*)wr, wb = *(const float4*)(wr + 4);
        double dots[4];
        #pragma unroll
        for (int t = 0; t < 4; ++t) {
            const float* xr = x + ((size_t)(t * 4096 + m)) * 512 + lane * 8;
            float4 xa = *(const float4*)xr, xb = *(const float4*)(xr + 4);
            double s = (double)xa.x * wa.x + (double)xa.y * wa.y + (double)xa.z * wa.z + (double)xa.w * wa.w
                     + (double)xb.x * wb.x + (double)xb.y * wb.y + (double)xb.z * wb.z + (double)xb.w * wb.w;
            #pragma unroll
            for (int off = 32; off > 0; off >>= 1) s += __shfl_xor(s, off);
            dots[t] = s;
        }
        if (lane == 0) {
            double scd = (double)ga[d] / sqrt((double)va[d] + 1e-5);
            double v = 0.0;
            #pragma unroll
            for (int t = 0; t < 4; ++t) {
                double yb = (dots[t] + (double)bi[d] - (double)mu[d]) * scd + (double)be[d];
                v = v + (yb - v) * 0.5;
                u64* wp = &packed[pidx(branch, t, m >> 9, m & 511, d >> 6)];
                u64 msk = 1ull << (d & 63);
                if (v >= 1.0) { atomicOr(wp, msk); v = 0.0; }
                else          { atomicAnd(wp, ~msk); }
            }
        }
    }
}

// ---------------- K2a: KV[e][d] popcount per (t,b,h) -> f16 fragment-major ----------------
__global__ __launch_bounds__(256) void k_kv(const u64* __restrict__ packed, short* __restrict__ kvf,
                                            u32* __restrict__ flags2z)
{
    __shared__ u64 km[512], vm[512];
    __shared__ u64 kc[64][8], vc[64][8];
    const int bx = blockIdx.x;
    const int t = bx >> 6, b = (bx >> 3) & 7, h = bx & 7;
    const int tid = threadIdx.x;
    if (flags2z && bx == 0 && tid == 0) flags2z[0] = 0;

    #pragma unroll
    for (int i = 0; i < 2; ++i) {
        int n = tid + i * 256;
        km[n] = packed[pidx(1, t, b, n, h)];
        vm[n] = packed[pidx(2, t, b, n, h)];
    }
    __syncthreads();
    #pragma unroll
    for (int i = 0; i < 2; ++i) {
        int f = tid + i * 256;
        int e = f >> 3, w = f & 7;
        u64 kr = 0ull, vr = 0ull;
        for (int j = 0; j < 64; ++j) {
            kr |= ((km[w * 64 + j] >> e) & 1ull) << j;
            vr |= ((vm[w * 64 + j] >> e) & 1ull) << j;
        }
        kc[e][w] = kr; vc[e][w] = vr;
    }
    __syncthreads();
    short* out = kvf + (size_t)bx * 4096;
    #pragma unroll
    for (int i = 0; i < 16; ++i) {
        int f = tid + i * 256;
        int j = f & 7, lane = (f >> 3) & 63, ks = (f >> 9) & 1, dsub = f >> 10;
        int e = ks * 32 + ((lane >> 4) & 3) * 8 + j;
        int d = dsub * 16 + (lane & 15);
        int s = 0;
        #pragma unroll
        for (int w = 0; w < 8; ++w) s += __popcll(kc[e][w] & vc[d][w]);
        _Float16 hv = (_Float16)(float)s;
        out[f] = *(short*)&hv;
    }
}

// ---------------- K2b: f16 MFMA q@KV + exact LIF(thr=0.5) -> s2 bits ----------------
__global__ __launch_bounds__(256, 1) void k_attn(const u64* __restrict__ packed,
                                                 const short* __restrict__ kvf,
                                                 u16* __restrict__ s2)
{
    const int bx = blockIdx.x;
    const int b = bx >> 5, h = (bx >> 2) & 7, nt = bx & 3;
    const int tid = threadIdx.x;
    const int wave = tid >> 6, lane = tid & 63;
    const int l15 = lane & 15, g = lane >> 4;
    const int n0 = nt * 128 + wave * 32;

    float v[2][4][4];
    #pragma unroll
    for (int ms = 0; ms < 2; ++ms)
        #pragma unroll
        for (int ds = 0; ds < 4; ++ds)
            #pragma unroll
            for (int r = 0; r < 4; ++r) v[ms][ds][r] = 0.f;

    for (int t = 0; t < 4; ++t) {
        short8 bf[4][2];
        const size_t kvbase = (size_t)(((t * 8 + b) * 8 + h)) * 4096;
        #pragma unroll
        for (int ds = 0; ds < 4; ++ds)
            #pragma unroll
            for (int ks = 0; ks < 2; ++ks)
                bf[ds][ks] = *(const short8*)&kvf[kvbase + (size_t)((ds * 2 + ks) * 64 + lane) * 8];
        u64 qm[2];
        #pragma unroll
        for (int ms = 0; ms < 2; ++ms)
            qm[ms] = packed[pidx(0, t, b, n0 + ms * 16 + l15, h)];

        f32x4 acc[2][4];
        #pragma unroll
        for (int ms = 0; ms < 2; ++ms)
            #pragma unroll
            for (int ds = 0; ds < 4; ++ds) acc[ms][ds] = (f32x4)0.0f;

        #pragma unroll
        for (int ks = 0; ks < 2; ++ks)
            #pragma unroll
            for (int ms = 0; ms < 2; ++ms) {
                u32 byte = (u32)(qm[ms] >> ((ks * 4 + g) * 8)) & 0xFFu;
                short8 af;
                #pragma unroll
                for (int j = 0; j < 8; ++j) af[j] = ((byte >> j) & 1u) ? (short)0x3C00 : (short)0;
                half8 av = *(half8*)&af;
                #pragma unroll
                for (int ds = 0; ds < 4; ++ds)
                    acc[ms][ds] = __builtin_amdgcn_mfma_f32_16x16x32_f16(av, *(half8*)&bf[ds][ks],
                                                                         acc[ms][ds], 0, 0, 0);
            }
        #pragma unroll
        for (int ms = 0; ms < 2; ++ms)
            #pragma unroll
            for (int ds = 0; ds < 4; ++ds)
                #pragma unroll
                for (int r = 0; r < 4; ++r) {
                    float y = acc[ms][ds][r] * 0.125f;
                    float vv = v[ms][ds][r];
                    vv = vv + (y - vv) * 0.5f;
                    bool s = vv >= 0.5f;
                    u64 bal = __ballot(s);
                    if (s) vv = 0.f;
                    v[ms][ds][r] = vv;
                    if (l15 == 0) {
                        int n = n0 + ms * 16 + g * 4 + r;
                        s2[((size_t)(t * 8 + b) * 512 + n) * 32 + h * 4 + ds] =
                            (u16)((bal >> (g * 16)) & 0xFFFFull);
                    }
                }
    }
}

// ---------------- repair2: fp64 recompute of flagged p-branch chains ----------------
__global__ __launch_bounds__(256) void k_repair2(
    const u16* __restrict__ s2,
    const float* __restrict__ pw, const float* __restrict__ pbi,
    const float* __restrict__ pga, const float* __restrict__ pbe,
    const float* __restrict__ pmu, const float* __restrict__ pva,
    const u32* __restrict__ flags, float* __restrict__ out)
{
    u32 n = flags[0]; if (n > CAP2) n = CAP2;
    int gw = (blockIdx.x * 256 + threadIdx.x) >> 6;
    int lane = threadIdx.x & 63;
    int nw = gridDim.x * 4;
    for (u32 i = gw; i < n; i += nw) {
        u32 e = flags[4 + i];
        int m = (e >> 9) & 4095, d = e & 511;
        const float* wr = pw + (size_t)d * 512 + lane * 8;
        float4 wa = *(const float4*)wr, wb = *(const float4*)(wr + 4);
        float we[8] = {wa.x, wa.y, wa.z, wa.w, wb.x, wb.y, wb.z, wb.w};
        double dots[4];
        #pragma unroll
        for (int t = 0; t < 4; ++t) {
            u16 wd = s2[((size_t)(t * 4096 + m)) * 32 + (lane >> 1)];
            int sh = (lane & 1) * 8;
            double s = 0.0;
            #pragma unroll
            for (int j = 0; j < 8; ++j)
                if ((wd >> (sh + j)) & 1) s += (double)we[j];
            #pragma unroll
            for (int off = 32; off > 0; off >>= 1) s += __shfl_xor(s, off);
            dots[t] = s;
        }
        if (lane == 0) {
            double scd = (double)pga[d] / sqrt((double)pva[d] + 1e-5);
            double v = 0.0;
            #pragma unroll
            for (int t = 0; t < 4; ++t) {
                double yb = (dots[t] + (double)pbi[d] - (double)pmu[d]) * scd + (double)pbe[d];
                v = v + (yb - v) * 0.5;
                bool s = v >= 1.0;
                out[((size_t)(t * 4096 + m)) * 512 + d] = s ? 1.0f : 0.0f;
                if (s) v = 0.0;
            }
        }
    }
}

extern "C" void kernel_launch(void* const* d_in, const int* in_sizes, int n_in,
                              void* d_out, int out_size, void* d_ws, size_t ws_size,
                              hipStream_t stream) {
    const float* x   = (const float*)d_in[0];
    const float* qw  = (const float*)d_in[1];
    const float* qb  = (const float*)d_in[2];
    const float* qga = (const float*)d_in[3];
    const float* qbe = (const float*)d_in[4];
    const float* qmu = (const float*)d_in[5];
    const float* qva = (const float*)d_in[6];
    const float* kw  = (const float*)d_in[7];
    const float* kb  = (const float*)d_in[8];
    const float* kga = (const float*)d_in[9];
    const float* kbe = (const float*)d_in[10];
    const float* kmu = (const float*)d_in[11];
    const float* kva = (const float*)d_in[12];
    const float* vw  = (const float*)d_in[13];
    const float* vb  = (const float*)d_in[14];
    const float* vga = (const float*)d_in[15];
    const float* vbe = (const float*)d_in[16];
    const float* vmu = (const float*)d_in[17];
    const float* vva_= (const float*)d_in[18];
    const float* pw  = (const float*)d_in[19];
    const float* pb  = (const float*)d_in[20];
    const float* pga = (const float*)d_in[21];
    const float* pbe = (const float*)d_in[22];
    const float* pmu = (const float*)d_in[23];
    const float* pva = (const float*)d_in[24];

    char* W = (char*)d_ws;
    u64*  packed = (u64*)W;                          // [0, 3M)
    short* kvf   = (short*)(W + (3u << 20));         // [3M, 5M)
    u16*  s2     = (u16*)(W + (5u << 20));           // [5M, 6M)
    short* wfh   = (short*)(W + (6u << 20));         // [6M, 8M)
    short* wfl   = (short*)(W + (8u << 20));         // [8M, 10M)
    short* xfh   = (short*)(W + (10u << 20));        // [10M, 26M)
    short* xfl   = (short*)(W + (26u << 20));        // [26M, 42M)
    u32*  flags1 = (u32*)(W + (3u << 20));           // transient [3M,6M), dead after repair1
    u32*  flags2b= (u32*)(W + (26u << 20));          // big path: xfl region, dead after k_branch
    u32*  flags2s= (u32*)W;                          // small path: packed region, dead after k_attn

    const bool big_ws = ws_size >= (44ull << 20);

    if (big_ws) {
        k_split_xw<<<4608, 256, 0, stream>>>(x, qw, kw, vw, pw, wfh, wfl, xfh, xfl, flags1);
        k_branch_p2<<<dim3(64, 12), 512, 0, stream>>>(
            xfh, xfl, wfh, wfl,
            qb, qga, qbe, qmu, qva,
            kb, kga, kbe, kmu, kva,
            vb, vga, vbe, vmu, vva_,
            packed, flags1);
    } else {
        k_split_xw<<<512, 256, 0, stream>>>(x, qw, kw, vw, pw, wfh, wfl, xfh, xfl, flags1);
        k_branch_v4<<<dim3(64, 12), 512, 0, stream>>>(
            x, wfh, wfl,
            qb, qga, qbe, qmu, qva,
            kb, kga, kbe, kmu, kva,
            vb, vga, vbe, vmu, vva_,
            packed, flags1);
    }
    k_repair1<<<256, 256, 0, stream>>>(
        x,
        qw, qb, qga, qbe, qmu, qva,
        kw, kb, kga, kbe, kmu, kva,
        vw, vb, vga, vbe, vmu, vva_,
        flags1, packed);
    k_kv<<<256, 256, 0, stream>>>(packed, kvf, big_ws ? flags2b : (u32*)nullptr);
    k_attn<<<256, 256, 0, stream>>>(packed, kvf, s2);
    if (big_ws) {
        k_pbranch_f2<<<dim3(64, 8), 512, 0, stream>>>(
            s2, wfh, wfl, pb, pga, pbe, pmu, pva, (float*)d_out, flags2b);
        k_repair2<<<128, 256, 0, stream>>>(
            s2, pw, pb, pga, pbe, pmu, pva, flags2b, (float*)d_out);
    } else {
        k_zero<<<1, 64, 0, stream>>>(flags2s);
        k_pbranch_f2<<<dim3(64, 8), 512, 0, stream>>>(
            s2, wfh, wfl, pb, pga, pbe, pmu, pva, (float*)d_out, flags2s);
        k_repair2<<<128, 256, 0, stream>>>(
            s2, pw, pb, pga, pbe, pmu, pva, flags2s, (float*)d_out);
    }
}